// Round 1
// baseline (228.285 us; speedup 1.0000x reference)
//
#include <hip/hip_runtime.h>
#include <math.h>

// Ising-style flip kernel: out = s * flip where
//   Js  = up + down + left + right (periodic wrap, radius 1)
//   de  = (2*s)*Js
//   p   = de <= 0 ? 1 : exp(-de)
//   flip = (rand < p) && (drop_rand > 0.5)  ->  -1 else +1
// Shapes: x, rand: (16,1,2048,2048) f32; drop_rand: (2048,2048) f32.

namespace {

constexpr int Bn  = 16;
constexpr int Hn  = 2048;
constexpr int Wn  = 2048;
constexpr int W4  = Wn / 4;        // 512  (float4 per row)
constexpr int HW4 = Hn * W4;       // 2^20 vec-elements per image

__global__ __launch_bounds__(256) void ising_flip_kernel(
    const float* __restrict__ x,
    const float* __restrict__ rnd,
    const float* __restrict__ drop,
    float* __restrict__ out)
{
    const int idx = blockIdx.x * blockDim.x + threadIdx.x;  // 0 .. 16M-1
    const int b   = idx >> 20;            // / HW4 (2^20)
    const int rem = idx & (HW4 - 1);
    const int h   = rem >> 9;             // / W4 (2^9)
    const int wv  = rem & (W4 - 1);

    const size_t img = (size_t)b * (size_t)(Hn * Wn);
    const float* xi  = x + img;
    const int row = h * Wn;
    const int c0  = wv * 4;

    // Center / vertical-neighbor rows as float4; horizontal edge scalars.
    const float4 sc = *(const float4*)(xi + row + c0);
    const int hu = (h == 0)      ? (Hn - 1) : (h - 1);
    const int hd = (h == Hn - 1) ? 0        : (h + 1);
    const float4 up = *(const float4*)(xi + hu * Wn + c0);
    const float4 dn = *(const float4*)(xi + hd * Wn + c0);
    const float lf = xi[row + ((c0 == 0)       ? (Wn - 1) : (c0 - 1))];
    const float rt = xi[row + ((c0 + 4 == Wn)  ? 0        : (c0 + 4))];

    const float4 rv = *(const float4*)(rnd + img + row + c0);
    const float4 dv = *(const float4*)(drop + row + c0);

    float s[4]  = {sc.x, sc.y, sc.z, sc.w};
    float u[4]  = {up.x, up.y, up.z, up.w};
    float dw[4] = {dn.x, dn.y, dn.z, dn.w};
    float r[4]  = {rv.x, rv.y, rv.z, rv.w};
    float m[4]  = {dv.x, dv.y, dv.z, dv.w};
    float o[4];

#pragma unroll
    for (int j = 0; j < 4; ++j) {
        const float left  = (j == 0) ? lf : s[j - 1];
        const float right = (j == 3) ? rt : s[j + 1];
        // Replicate reference op order exactly:
        // Js = ((up + down) + left) + right ; de = (2*s)*Js
        const float js = ((u[j] + dw[j]) + left) + right;
        const float de = (2.0f * s[j]) * js;

        bool lt;
        if (de <= 0.0f) {
            lt = true;                       // p = 1; rand in [0,1) < 1 always
        } else {
            float p = expf(-de);
            // Tie band: if rand is within a few ulps of p, recompute the
            // correctly-rounded f32 exp via double to match the host ref's
            // flip decision. Taken by ~tens of lanes out of 64M.
            if (fabsf(r[j] - p) <= p * 1.0e-6f) {
                p = (float)exp(-(double)de);
            }
            lt = r[j] < p;
        }
        const bool flip = lt && (m[j] > 0.5f);
        o[j] = flip ? -s[j] : s[j];
    }

    *(float4*)(out + img + row + c0) = make_float4(o[0], o[1], o[2], o[3]);
}

} // namespace

extern "C" void kernel_launch(void* const* d_in, const int* in_sizes, int n_in,
                              void* d_out, int out_size, void* d_ws, size_t ws_size,
                              hipStream_t stream)
{
    const float* x    = (const float*)d_in[0];
    const float* rnd  = (const float*)d_in[1];
    const float* drop = (const float*)d_in[2];
    float* out        = (float*)d_out;

    constexpr int total4 = Bn * HW4;       // 16,777,216 float4 elements
    dim3 block(256);
    dim3 grid(total4 / 256);               // 65,536 blocks, exact cover
    hipLaunchKernelGGL(ising_flip_kernel, grid, block, 0, stream,
                       x, rnd, drop, out);
}

// Round 2
// 156.684 us; speedup vs baseline: 1.4570x; 1.4570x over previous
//
#include <hip/hip_runtime.h>
#include <math.h>

// Ising-style flip: out = s * flip where
//   Js = up+down+left+right (periodic, r=1); de = (2*s)*Js
//   p  = de<=0 ? 1 : exp(-de); flip = (rand<p)&&(drop>0.5) ? -1 : +1
// x, rand: (16,1,2048,2048) f32; drop: (2048,2048) f32.
//
// R2: 4-row x 4-col tile per thread (x fetch 3x -> 1.5x), XCD swizzle so
// adjacent strips share an XCD L2 (boundary rows -> L2 hits), nontemporal
// rand loads + out stores (no L2 pollution from zero-reuse streams).

namespace {

constexpr int Bn  = 16;
constexpr int Hn  = 2048;
constexpr int Wn  = 2048;
constexpr int W4  = Wn / 4;             // 512 float4 per row
constexpr int RPT = 4;                  // rows per thread
constexpr int HS  = Hn / RPT;           // 512 strips per image
constexpr int NTHREADS = Bn * HS * W4;  // 4,194,304
constexpr int NBLK = NTHREADS / 256;    // 16,384
constexpr int NXCD = 8;
constexpr int BLK_PER_XCD = NBLK / NXCD; // 2048

typedef float f4 __attribute__((ext_vector_type(4)));

__global__ __launch_bounds__(256) void ising_flip_kernel(
    const float* __restrict__ x,
    const float* __restrict__ rnd,
    const float* __restrict__ drop,
    float* __restrict__ out)
{
    // XCD swizzle: physical block b lands on XCD b%8 (round-robin dispatch).
    // Map so each XCD owns a contiguous logical chunk -> vertical neighbors
    // share that XCD's L2.
    const int phys    = blockIdx.x;
    const int logical = (phys & (NXCD - 1)) * BLK_PER_XCD + (phys >> 3);
    const int tid     = logical * 256 + (int)threadIdx.x;

    const int wv = tid & (W4 - 1);          // col-vec, fastest (coalesced)
    const int hs = (tid >> 9) & (HS - 1);   // row strip
    const int b  = tid >> 18;               // image

    const int    c0  = wv * 4;
    const int    h0  = hs * RPT;
    const size_t img = (size_t)b * (size_t)(Hn * Wn);
    const float* xi  = x + img;

    // 6 x-rows cover 4 output rows (+1 up, +1 down). Only k=0 / k=5 can wrap.
    f4 xr[RPT + 2];
#pragma unroll
    for (int k = 0; k < RPT + 2; ++k) {
        int hr = h0 - 1 + k;
        hr = (hr < 0) ? (Hn - 1) : ((hr >= Hn) ? 0 : hr);
        xr[k] = *(const f4*)(xi + (size_t)hr * Wn + c0);
    }

    const int cl = (c0 == 0)      ? (Wn - 1) : (c0 - 1);
    const int cr = (c0 + 4 == Wn) ? 0        : (c0 + 4);

    float lf[RPT], rt[RPT];
    f4 rv[RPT], dv[RPT];
#pragma unroll
    for (int i = 0; i < RPT; ++i) {
        const int row = (h0 + i) * Wn;
        lf[i] = xi[row + cl];
        rt[i] = xi[row + cr];
        rv[i] = __builtin_nontemporal_load((const f4*)(rnd + img + row + c0));
        dv[i] = *(const f4*)(drop + row + c0);
    }

#pragma unroll
    for (int i = 0; i < RPT; ++i) {
        const f4 sc = xr[i + 1];
        const f4 up = xr[i];
        const f4 dn = xr[i + 2];
        f4 o;
#pragma unroll
        for (int j = 0; j < 4; ++j) {
            const float s     = sc[j];
            const float left  = (j == 0) ? lf[i] : sc[j - 1];
            const float right = (j == 3) ? rt[i] : sc[j + 1];
            // Reference op order: Js = ((up+down)+left)+right; de = (2*s)*Js
            const float js = ((up[j] + dn[j]) + left) + right;
            const float de = (2.0f * s) * js;

            bool lt;
            if (de <= 0.0f) {
                lt = true;                    // p = 1; rand in [0,1) < 1
            } else {
                float p = expf(-de);
                // Tie band: near-equal rand vs p -> recompute exp in double
                // to match the host reference's correctly-rounded decision.
                if (fabsf(rv[i][j] - p) <= p * 1.0e-6f) {
                    p = (float)exp(-(double)de);
                }
                lt = rv[i][j] < p;
            }
            const bool flip = lt && (dv[i][j] > 0.5f);
            o[j] = flip ? -s : s;
        }
        __builtin_nontemporal_store(o, (f4*)(out + img + (size_t)(h0 + i) * Wn + c0));
    }
}

} // namespace

extern "C" void kernel_launch(void* const* d_in, const int* in_sizes, int n_in,
                              void* d_out, int out_size, void* d_ws, size_t ws_size,
                              hipStream_t stream)
{
    const float* x    = (const float*)d_in[0];
    const float* rnd  = (const float*)d_in[1];
    const float* drop = (const float*)d_in[2];
    float* out        = (float*)d_out;

    hipLaunchKernelGGL(ising_flip_kernel, dim3(NBLK), dim3(256), 0, stream,
                       x, rnd, drop, out);
}

// Round 3
// 151.385 us; speedup vs baseline: 1.5080x; 1.0350x over previous
//
#include <hip/hip_runtime.h>
#include <math.h>

// Ising-style flip: out = s * flip where
//   Js = up+down+left+right (periodic, r=1); de = (2*s)*Js
//   p  = de<=0 ? 1 : exp(-de); flip = (rand<p)&&(drop>0.5) ? -1 : +1
// x, rand: (16,1,2048,2048) f32; drop: (2048,2048) f32.
//
// R3: halo columns via wave shuffles (neighbor lanes already hold them in
// registers) instead of 8 gather-style scalar loads per thread; only lanes
// 0/63 do a real edge load (1 transaction, exec-masked). Keeps R2's 4-row
// tile, XCD swizzle, NT rand loads + NT stores.

namespace {

constexpr int Bn  = 16;
constexpr int Hn  = 2048;
constexpr int Wn  = 2048;
constexpr int W4  = Wn / 4;             // 512 float4 per row
constexpr int RPT = 4;                  // rows per thread
constexpr int HS  = Hn / RPT;           // 512 strips per image
constexpr int NTHREADS = Bn * HS * W4;  // 4,194,304
constexpr int NBLK = NTHREADS / 256;    // 16,384
constexpr int NXCD = 8;
constexpr int BLK_PER_XCD = NBLK / NXCD; // 2048

typedef float f4 __attribute__((ext_vector_type(4)));

__global__ __launch_bounds__(256) void ising_flip_kernel(
    const float* __restrict__ x,
    const float* __restrict__ rnd,
    const float* __restrict__ drop,
    float* __restrict__ out)
{
    // XCD swizzle: physical block b lands on XCD b%8 (round-robin dispatch).
    // Map so each XCD owns a contiguous logical chunk -> vertical neighbors
    // share that XCD's L2.
    const int phys    = blockIdx.x;
    const int logical = (phys & (NXCD - 1)) * BLK_PER_XCD + (phys >> 3);
    const int tid     = logical * 256 + (int)threadIdx.x;
    const int lane    = (int)threadIdx.x & 63;

    const int wv = tid & (W4 - 1);          // col-vec, fastest (coalesced)
    const int hs = (tid >> 9) & (HS - 1);   // row strip
    const int b  = tid >> 18;               // image

    const int    c0  = wv * 4;
    const int    h0  = hs * RPT;
    const size_t img = (size_t)b * (size_t)(Hn * Wn);
    const float* xi  = x + img;

    // 6 x-rows cover 4 output rows (+1 up, +1 down). Only k=0 / k=5 can wrap.
    f4 xr[RPT + 2];
#pragma unroll
    for (int k = 0; k < RPT + 2; ++k) {
        int hr = h0 - 1 + k;
        hr = (hr < 0) ? (Hn - 1) : ((hr >= Hn) ? 0 : hr);
        xr[k] = *(const f4*)(xi + (size_t)hr * Wn + c0);
    }

    f4 rv[RPT], dv[RPT];
#pragma unroll
    for (int i = 0; i < RPT; ++i) {
        const int row = (h0 + i) * Wn;
        rv[i] = __builtin_nontemporal_load((const f4*)(rnd + img + row + c0));
        dv[i] = *(const f4*)(drop + row + c0);
    }

    // Halo columns: neighbor lane already holds them. Lane l's left scalar is
    // lane l-1's xr[i+1][3]; right scalar is lane l+1's xr[i+1][0]. Only the
    // wave-edge lanes (0 / 63) need a real load (also covers the W-wrap).
    float lf[RPT], rt[RPT];
#pragma unroll
    for (int i = 0; i < RPT; ++i) {
        lf[i] = __shfl_up(xr[i + 1][3], 1);
        rt[i] = __shfl_down(xr[i + 1][0], 1);
    }
    if (lane == 0) {
        const int cl = (c0 == 0) ? (Wn - 1) : (c0 - 1);
#pragma unroll
        for (int i = 0; i < RPT; ++i) lf[i] = xi[(h0 + i) * Wn + cl];
    }
    if (lane == 63) {
        const int cr = (c0 + 4 == Wn) ? 0 : (c0 + 4);
#pragma unroll
        for (int i = 0; i < RPT; ++i) rt[i] = xi[(h0 + i) * Wn + cr];
    }

#pragma unroll
    for (int i = 0; i < RPT; ++i) {
        const f4 sc = xr[i + 1];
        const f4 up = xr[i];
        const f4 dn = xr[i + 2];
        f4 o;
#pragma unroll
        for (int j = 0; j < 4; ++j) {
            const float s     = sc[j];
            const float left  = (j == 0) ? lf[i] : sc[j - 1];
            const float right = (j == 3) ? rt[i] : sc[j + 1];
            // Reference op order: Js = ((up+down)+left)+right; de = (2*s)*Js
            const float js = ((up[j] + dn[j]) + left) + right;
            const float de = (2.0f * s) * js;

            bool lt;
            if (de <= 0.0f) {
                lt = true;                    // p = 1; rand in [0,1) < 1
            } else {
                float p = expf(-de);
                // Tie band: near-equal rand vs p -> recompute exp in double
                // to match the host reference's correctly-rounded decision.
                if (fabsf(rv[i][j] - p) <= p * 1.0e-6f) {
                    p = (float)exp(-(double)de);
                }
                lt = rv[i][j] < p;
            }
            const bool flip = lt && (dv[i][j] > 0.5f);
            o[j] = flip ? -s : s;
        }
        __builtin_nontemporal_store(o, (f4*)(out + img + (size_t)(h0 + i) * Wn + c0));
    }
}

} // namespace

extern "C" void kernel_launch(void* const* d_in, const int* in_sizes, int n_in,
                              void* d_out, int out_size, void* d_ws, size_t ws_size,
                              hipStream_t stream)
{
    const float* x    = (const float*)d_in[0];
    const float* rnd  = (const float*)d_in[1];
    const float* drop = (const float*)d_in[2];
    float* out        = (float*)d_out;

    hipLaunchKernelGGL(ising_flip_kernel, dim3(NBLK), dim3(256), 0, stream,
                       x, rnd, drop, out);
}